// Round 13
// baseline (485.761 us; speedup 1.0000x reference)
//
#include <hip/hip_runtime.h>
#include <cstdint>

#define N_DATA 16384
#define DIM 512
#define MEM 512
#define KSEL 4096
#define NH 8
#define DH 64
#define KVDIM 1024
#define SCALE 0.125f
#define ZCNT 12288.0f
#define LN_EPS 1e-5f
#define NSPLIT 4
#define ROWS_SP (KSEL / NSPLIT)

typedef unsigned short u16;
using short8 = __attribute__((ext_vector_type(8))) short;
using f32x4  = __attribute__((ext_vector_type(4))) float;

// ---------- scalar helpers ----------
__device__ __forceinline__ unsigned fenc(float x) {
    unsigned u = __float_as_uint(x);
    return (u & 0x80000000u) ? ~u : (u | 0x80000000u);
}
__device__ __forceinline__ u16 f2bf(float x) {          // RNE f32 -> bf16
    unsigned u = __float_as_uint(x);
    u += 0x7fffu + ((u >> 16) & 1u);
    return (u16)(u >> 16);
}
__device__ __forceinline__ float bf2f(u16 h) { return __uint_as_float(((unsigned)h) << 16); }

__device__ __forceinline__ float waveSum(float v) {
#pragma unroll
    for (int o = 32; o > 0; o >>= 1) v += __shfl_down(v, o, 64);
    return v;
}
// blockDim.x == 256 assumed (4 waves)
__device__ float blockSum(float v) {
    __shared__ float sh[4];
    __syncthreads();
    v = waveSum(v);
    if ((threadIdx.x & 63) == 0) sh[threadIdx.x >> 6] = v;
    __syncthreads();
    if (threadIdx.x == 0) { float s = sh[0]; for (int i = 1; i < 4; ++i) s += sh[i]; sh[0] = s; }
    __syncthreads();
    return sh[0];
}

// ---------- global -> LDS async staging of a ROWS x 32 bf16 tile ----------
template<int ROWS, int NW, bool GATHER>
__device__ __forceinline__ void stage_tile(const u16* __restrict__ src, int ld, int k0,
                                           int row0, const int* __restrict__ gidx,
                                           u16* lds, int wave)
{
    constexpr int NI = ROWS / 16;
    const int lane = threadIdx.x & 63;
#pragma unroll
    for (int i = wave; i < NI; i += NW) {
        const int ch = i * 64 + lane;
        const int r = ch >> 2, cc = ch & 3;
        int rg = row0 + r;
        if (GATHER) rg = gidx[rg];
        const u16* g = src + (long)rg * ld + k0 + cc * 8;
        u16* l = lds + i * 512;
        __builtin_amdgcn_global_load_lds((const __attribute__((address_space(1))) void*)g,
                                         (__attribute__((address_space(3))) void*)l,
                                         16, 0, 0);
    }
}

// ---------- bf16 MFMA GEMM (BK=32): C = alpha*A*B^T ----------
// EPI: 0 = store fp32, 1 = store bf16, 2 = rowmax atomic into simenc,
//      3 = kv split: K-half (bn0<512) -> C[ldc=1024]; V-half -> vTo transposed
// LOSS: block (0,0) additionally reduces lse/mlp scalars into o2 after its store
template<int WM, int WN, bool GATHER, int EPI, bool BIAS, bool LOSS>
__global__ __launch_bounds__(WM * WN * 64)
void mfma_gemm(const u16* __restrict__ A, const u16* __restrict__ B,
               const float* __restrict__ bias, const int* __restrict__ gidx,
               void* __restrict__ Cv, unsigned* __restrict__ simenc,
               u16* __restrict__ vTo,
               const float* __restrict__ lseIn, const float* __restrict__ mlpIn,
               float* __restrict__ o2,
               int K, int lda, int ldb, int ldc,
               long zsA, long zsB, long zsC, int zdiv, long zsplitC, float alpha)
{
    constexpr int BM = WM * 64, BN = WN * 64, NW = WM * WN;
    __shared__ __align__(16) u16 As[BM * 32];
    __shared__ __align__(16) u16 Bs[BN * 32];

    const int t = threadIdx.x;
    const int wave = t >> 6, lane = t & 63;
    const int wr = wave / WN, wc = wave % WN;
    const int l15 = lane & 15, l4 = lane >> 4;
    const int bm0 = blockIdx.x * BM, bn0 = blockIdx.y * BN;
    const int zs = (int)blockIdx.z % zdiv;
    const int zh = (int)blockIdx.z / zdiv;
    A += (long)zh * zsA;
    B += (long)zh * zsB;

    f32x4 acc[4][4];
#pragma unroll
    for (int i = 0; i < 4; ++i)
#pragma unroll
        for (int j = 0; j < 4; ++j)
#pragma unroll
            for (int r = 0; r < 4; ++r) acc[i][j][r] = 0.f;

    const int Kd = K / zdiv;
    const int kbeg = zs * Kd;
    for (int k0 = kbeg; k0 < kbeg + Kd; k0 += 32) {
        stage_tile<BM, NW, GATHER>(A, lda, k0, bm0, gidx, As, wave);
        stage_tile<BN, NW, false>(B, ldb, k0, bn0, nullptr, Bs, wave);
        __syncthreads();
        short8 a[4], b[4];
#pragma unroll
        for (int fm = 0; fm < 4; ++fm)
            a[fm] = *(const short8*)(As + (wr * 64 + fm * 16 + l15) * 32 + l4 * 8);
#pragma unroll
        for (int fn = 0; fn < 4; ++fn)
            b[fn] = *(const short8*)(Bs + (wc * 64 + fn * 16 + l15) * 32 + l4 * 8);
#pragma unroll
        for (int fm = 0; fm < 4; ++fm)
#pragma unroll
            for (int fn = 0; fn < 4; ++fn)
                acc[fm][fn] = __builtin_amdgcn_mfma_f32_16x16x32_bf16(a[fm], b[fn], acc[fm][fn], 0, 0, 0);
        __syncthreads();
    }

    if (EPI == 2) {
#pragma unroll
        for (int fm = 0; fm < 4; ++fm)
#pragma unroll
            for (int r = 0; r < 4; ++r) {
                float mx = acc[fm][0][r];
#pragma unroll
                for (int fn = 1; fn < 4; ++fn) mx = fmaxf(mx, acc[fm][fn][r]);
#pragma unroll
                for (int o = 8; o >= 1; o >>= 1) mx = fmaxf(mx, __shfl_xor(mx, o, 64));
                if (l15 == 0) {
                    const int row = bm0 + wr * 64 + fm * 16 + l4 * 4 + r;
                    atomicMax(simenc + row, fenc(alpha * mx));
                }
            }
    } else if (EPI == 0) {
        float* C = (float*)Cv + (long)zh * zsC + (long)zs * zsplitC;
#pragma unroll
        for (int fm = 0; fm < 4; ++fm)
#pragma unroll
            for (int fn = 0; fn < 4; ++fn)
#pragma unroll
                for (int r = 0; r < 4; ++r) {
                    const int row = bm0 + wr * 64 + fm * 16 + l4 * 4 + r;
                    const int col = bn0 + wc * 64 + fn * 16 + l15;
                    float v = alpha * acc[fm][fn][r];
                    if (BIAS) v += bias[col];
                    C[(long)row * ldc + col] = v;
                }
    } else if (EPI == 1) {
        u16* C = (u16*)Cv + (long)zh * zsC + (long)zs * zsplitC;
#pragma unroll
        for (int fm = 0; fm < 4; ++fm)
#pragma unroll
            for (int fn = 0; fn < 4; ++fn)
#pragma unroll
                for (int r = 0; r < 4; ++r) {
                    const int row = bm0 + wr * 64 + fm * 16 + l4 * 4 + r;
                    const int col = bn0 + wc * 64 + fn * 16 + l15;
                    float v = alpha * acc[fm][fn][r];
                    if (BIAS) v += bias[col];
                    C[(long)row * ldc + col] = f2bf(v);
                }
    } else {   // EPI == 3: kv projection split write
        if (bn0 < 512) {        // K half -> kvsel rows (ld 1024)
            u16* C = (u16*)Cv;
#pragma unroll
            for (int fm = 0; fm < 4; ++fm)
#pragma unroll
                for (int fn = 0; fn < 4; ++fn)
#pragma unroll
                    for (int r = 0; r < 4; ++r) {
                        const int row = bm0 + wr * 64 + fm * 16 + l4 * 4 + r;
                        const int col = bn0 + wc * 64 + fn * 16 + l15;
                        C[(long)row * ldc + col] = f2bf(alpha * acc[fm][fn][r]);
                    }
        } else {                // V half -> vTo[d][j] transposed (ld 4096)
#pragma unroll
            for (int fm = 0; fm < 4; ++fm)
#pragma unroll
                for (int fn = 0; fn < 4; ++fn) {
                    const int d = bn0 + wc * 64 + fn * 16 + l15 - 512;
                    const int row0 = bm0 + wr * 64 + fm * 16 + l4 * 4;
                    ushort4 pw;
                    pw.x = f2bf(alpha * acc[fm][fn][0]);
                    pw.y = f2bf(alpha * acc[fm][fn][1]);
                    pw.z = f2bf(alpha * acc[fm][fn][2]);
                    pw.w = f2bf(alpha * acc[fm][fn][3]);
                    *(ushort4*)(vTo + (long)d * 4096 + row0) = pw;
                }
        }
    }

    if (LOSS) {
        if (blockIdx.x == 0 && blockIdx.y == 0) {
            float s1 = 0.f, s2 = 0.f;
            for (int i = t; i < N_DATA; i += WM * WN * 64) {
                s1 += mlpIn[i];
                const float l = lseIn[i];
                s2 += l * l;
            }
            s1 = blockSum(s1);
            s2 = blockSum(s2);
            if (t == 0) { o2[0] = -s1 * (1.f / N_DATA); o2[1] = s2 * (1.f / N_DATA); }
        }
    }
}

// ---------- full-row GEMM (BM=64, BN=512, K=512) + fused log-softmax epilogue ----------
__global__ __launch_bounds__(512)
void mfma_gemm_sm(const u16* __restrict__ A, const u16* __restrict__ B,
                  u16* __restrict__ Obf, float* __restrict__ simf,
                  float* __restrict__ lse, float* __restrict__ mlp, float alpha)
{
    __shared__ __align__(16) u16 As[64 * 32];     // 4KB
    __shared__ __align__(16) u16 Bs[512 * 32];    // 32KB
    const int t = threadIdx.x, wave = t >> 6, lane = t & 63;
    const int wc = wave;
    const int l15 = lane & 15, l4 = lane >> 4;
    const int bm0 = blockIdx.x * 64;

    f32x4 acc[4][4];
#pragma unroll
    for (int i = 0; i < 4; ++i)
#pragma unroll
        for (int j = 0; j < 4; ++j)
#pragma unroll
            for (int r = 0; r < 4; ++r) acc[i][j][r] = 0.f;

    for (int k0 = 0; k0 < 512; k0 += 32) {
        stage_tile<64, 8, false>(A, 512, k0, bm0, nullptr, As, wave);
        stage_tile<512, 8, false>(B, 512, k0, 0, nullptr, Bs, wave);
        __syncthreads();
        short8 a[4], b[4];
#pragma unroll
        for (int fm = 0; fm < 4; ++fm)
            a[fm] = *(const short8*)(As + (fm * 16 + l15) * 32 + l4 * 8);
#pragma unroll
        for (int fn = 0; fn < 4; ++fn)
            b[fn] = *(const short8*)(Bs + (wc * 64 + fn * 16 + l15) * 32 + l4 * 8);
#pragma unroll
        for (int fm = 0; fm < 4; ++fm)
#pragma unroll
            for (int fn = 0; fn < 4; ++fn)
                acc[fm][fn] = __builtin_amdgcn_mfma_f32_16x16x32_bf16(a[fm], b[fn], acc[fm][fn], 0, 0, 0);
        __syncthreads();
    }

    float* red  = (float*)As;          // [64][8]
    float* rowv = (float*)Bs;          // [64] m + [64] l

#pragma unroll
    for (int fm = 0; fm < 4; ++fm)
#pragma unroll
        for (int r = 0; r < 4; ++r) {
            float mx = alpha * acc[fm][0][r];
#pragma unroll
            for (int fn = 1; fn < 4; ++fn) mx = fmaxf(mx, alpha * acc[fm][fn][r]);
#pragma unroll
            for (int o = 1; o <= 8; o <<= 1) mx = fmaxf(mx, __shfl_xor(mx, o, 64));
            if (l15 == 0) red[(fm * 16 + l4 * 4 + r) * 8 + wc] = mx;
        }
    __syncthreads();
    if (t < 64) {
        float mx = red[t * 8];
#pragma unroll
        for (int j = 1; j < 8; ++j) mx = fmaxf(mx, red[t * 8 + j]);
        rowv[t] = mx;
    }
    __syncthreads();
#pragma unroll
    for (int fm = 0; fm < 4; ++fm)
#pragma unroll
        for (int r = 0; r < 4; ++r) {
            const int rl = fm * 16 + l4 * 4 + r;
            const float m = rowv[rl];
            float s = 0.f;
#pragma unroll
            for (int fn = 0; fn < 4; ++fn) s += __expf(alpha * acc[fm][fn][r] - m);
#pragma unroll
            for (int o = 1; o <= 8; o <<= 1) s += __shfl_xor(s, o, 64);
            if (l15 == 0) red[rl * 8 + wc] = s;
        }
    __syncthreads();
    if (t < 64) {
        float s = 0.f;
#pragma unroll
        for (int j = 0; j < 8; ++j) s += red[t * 8 + j];
        const float m = rowv[t];
        const float l = m + __logf(s);
        const int gr = bm0 + t;
        simf[gr] = m; lse[gr] = l; mlp[gr] = m - l;
        rowv[64 + t] = l;
    }
    __syncthreads();
#pragma unroll
    for (int fm = 0; fm < 4; ++fm)
#pragma unroll
        for (int r = 0; r < 4; ++r) {
            const int rl = fm * 16 + l4 * 4 + r;
            const float l = rowv[64 + rl];
#pragma unroll
            for (int fn = 0; fn < 4; ++fn) {
                const int col = wc * 64 + fn * 16 + l15;
                Obf[(long)(bm0 + rl) * 512 + col] = f2bf(__expf(alpha * acc[fm][fn][r] - l));
            }
        }
}

// ---------- Wm GEMM + bias + residual + LayerNorm, full-row BM=16 (32 blocks) ----------
// also zeroes simenc; optionally writes M^T bf16 (last layer)
__global__ __launch_bounds__(512)
void wmln(const u16* __restrict__ A, const u16* __restrict__ BT,
          const float* __restrict__ bias, const float* __restrict__ Min,
          float* __restrict__ Mout, u16* __restrict__ Mbf,
          unsigned* __restrict__ simz, u16* __restrict__ MTout)
{
    __shared__ __align__(16) u16 As[16 * 32];      // 1KB
    __shared__ __align__(16) u16 Bs[512 * 32];     // 32KB
    __shared__ float red[16][8], red2[16][8], rowv[32];
    const int t = threadIdx.x, wave = t >> 6, lane = t & 63;
    const int wc = wave;
    const int l15 = lane & 15, l4 = lane >> 4;
    const int bm0 = blockIdx.x * 16;

    simz[blockIdx.x * 512 + t] = 0u;   // 32*512 == 16384

    f32x4 acc[4];
#pragma unroll
    for (int fn = 0; fn < 4; ++fn)
#pragma unroll
        for (int r = 0; r < 4; ++r) acc[fn][r] = 0.f;

    for (int k0 = 0; k0 < 512; k0 += 32) {
        stage_tile<16, 8, false>(A, 512, k0, bm0, nullptr, As, wave);
        stage_tile<512, 8, false>(BT, 512, k0, 0, nullptr, Bs, wave);
        __syncthreads();
        const short8 a = *(const short8*)(As + l15 * 32 + l4 * 8);
#pragma unroll
        for (int fn = 0; fn < 4; ++fn) {
            const short8 b = *(const short8*)(Bs + (wc * 64 + fn * 16 + l15) * 32 + l4 * 8);
            acc[fn] = __builtin_amdgcn_mfma_f32_16x16x32_bf16(a, b, acc[fn], 0, 0, 0);
        }
        __syncthreads();
    }

    float v[4][4];
#pragma unroll
    for (int fn = 0; fn < 4; ++fn) {
        const int col = wc * 64 + fn * 16 + l15;
        const float bi = bias[col];
#pragma unroll
        for (int r = 0; r < 4; ++r) {
            const int row = bm0 + l4 * 4 + r;
            v[fn][r] = acc[fn][r] + bi + Min[(long)row * 512 + col];
        }
    }
#pragma unroll
    for (int r = 0; r < 4; ++r) {
        float s = 0.f, s2 = 0.f;
#pragma unroll
        for (int fn = 0; fn < 4; ++fn) { const float x = v[fn][r]; s += x; s2 += x * x; }
#pragma unroll
        for (int o = 1; o <= 8; o <<= 1) { s += __shfl_xor(s, o, 64); s2 += __shfl_xor(s2, o, 64); }
        if (l15 == 0) { red[l4 * 4 + r][wc] = s; red2[l4 * 4 + r][wc] = s2; }
    }
    __syncthreads();
    if (t < 16) {
        float s = 0.f, s2 = 0.f;
#pragma unroll
        for (int j = 0; j < 8; ++j) { s += red[t][j]; s2 += red2[t][j]; }
        const float mu = s * (1.f / 512.f);
        const float var = s2 * (1.f / 512.f) - mu * mu;
        rowv[t] = mu;
        rowv[16 + t] = rsqrtf(var + LN_EPS);
    }
    __syncthreads();
#pragma unroll
    for (int fn = 0; fn < 4; ++fn) {
        const int col = wc * 64 + fn * 16 + l15;
#pragma unroll
        for (int r = 0; r < 4; ++r) {
            const int rl = l4 * 4 + r;
            const float y = (v[fn][r] - rowv[rl]) * rowv[16 + rl];
            Mout[(long)(bm0 + rl) * 512 + col] = y;
            Mbf [(long)(bm0 + rl) * 512 + col] = f2bf(y);
            if (MTout) MTout[(long)col * 512 + (bm0 + rl)] = f2bf(y);
        }
    }
}

// ---------- fused flash attention (q-proj fused, double-buffered K/V, last-block combine) ----------
__global__ __launch_bounds__(256)
void flash_att(const u16* __restrict__ Mbf, const u16* __restrict__ WqT,
               const u16* __restrict__ KV, const u16* __restrict__ VT,
               float* __restrict__ oPart, float* __restrict__ mPart,
               float* __restrict__ lPart, u16* __restrict__ o_bf,
               unsigned* __restrict__ cnt)
{
    __shared__ __align__(16) u16 Qs[64 * 64];
    __shared__ __align__(16) u16 Ks[2][64 * 64];
    __shared__ __align__(16) u16 Vs[2][64 * 64];
    __shared__ __align__(16) u16 Ps[4][16 * 72];
    __shared__ int isLast;

    const int qt = blockIdx.x, h = blockIdx.y, sp = blockIdx.z;
    const int t = threadIdx.x, wave = t >> 6, lane = t & 63;
    const int l15 = lane & 15, l4 = lane >> 4;

    const u16* Kg = KV + ((long)sp * ROWS_SP) * 1024 + h * 64;
    const u16* Vg = VT + ((long)h * 64) * 4096 + sp * ROWS_SP;

    auto stageKV = [&](int kt, int buf) {
        const u16* Kt = Kg + (long)(kt * 64) * 1024;
        const u16* Vt = Vg + kt * 64;
#pragma unroll
        for (int i = wave; i < 8; i += 4) {
            const int ch = i * 64 + lane, r = ch >> 3, s = ch & 7;
            __builtin_amdgcn_global_load_lds(
                (const __attribute__((address_space(1))) void*)(Kt + (long)r * 1024 + ((s ^ (r & 7)) * 8)),
                (__attribute__((address_space(3))) void*)(Ks[buf] + i * 512), 16, 0, 0);
        }
#pragma unroll
        for (int i = wave; i < 8; i += 4) {
            const int ch = i * 64 + lane, r = ch >> 3, s = ch & 7;
            __builtin_amdgcn_global_load_lds(
                (const __attribute__((address_space(1))) void*)(Vt + (long)r * 4096 + ((s ^ (r & 7)) * 8)),
                (__attribute__((address_space(3))) void*)(Vs[buf] + i * 512), 16, 0, 0);
        }
    };

    stageKV(0, 0);

    // q-projection in registers
    f32x4 accq[4];
#pragma unroll
    for (int fn = 0; fn < 4; ++fn)
#pragma unroll
        for (int r = 0; r < 4; ++r) accq[fn][r] = 0.f;
    {
        const u16* Ag = Mbf + (long)(qt * 64 + wave * 16 + l15) * 512 + l4 * 8;
        const u16* Bg = WqT + (long)(h * 64 + l15) * 512 + l4 * 8;
#pragma unroll 4
        for (int k0 = 0; k0 < 512; k0 += 32) {
            const short8 a = *(const short8*)(Ag + k0);
#pragma unroll
            for (int fn = 0; fn < 4; ++fn) {
                const short8 b = *(const short8*)(Bg + (long)fn * 16 * 512 + k0);
                accq[fn] = __builtin_amdgcn_mfma_f32_16x16x32_bf16(a, b, accq[fn], 0, 0, 0);
            }
        }
    }
#pragma unroll
    for (int fn = 0; fn < 4; ++fn)
#pragma unroll
        for (int r = 0; r < 4; ++r) {
            const int qrow = wave * 16 + l4 * 4 + r;
            const int col = fn * 16 + l15;
            Qs[qrow * 64 + (((col >> 3) ^ (qrow & 7)) << 3) + (col & 7)] = f2bf(accq[fn][r]);
        }
    __syncthreads();

    const int qr = wave * 16 + l15;
    short8 qf0 = *(const short8*)(Qs + qr * 64 + ((0 * 4 + l4) ^ (qr & 7)) * 8);
    short8 qf1 = *(const short8*)(Qs + qr * 64 + ((1 * 4 + l4) ^ (qr & 7)) * 8);

    float m = -3.0e38f, lsum = 0.f;
    f32x4 acc_o[4];
#pragma unroll
    for (int nf = 0; nf < 4; ++nf)
#pragma unroll
        for (int r = 0; r < 4; ++r) acc_o[nf][r] = 0.f;

    u16* myP = &Ps[wave][0];
    constexpr int NT = ROWS_SP / 64;
    int cur = 0;

    for (int kt = 0; kt < NT; ++kt) {
        if (kt + 1 < NT) stageKV(kt + 1, cur ^ 1);
        const u16* Kc = Ks[cur];
        const u16* Vc = Vs[cur];
        f32x4 acc_s[4];
#pragma unroll
        for (int mf = 0; mf < 4; ++mf) {
#pragma unroll
            for (int r = 0; r < 4; ++r) acc_s[mf][r] = 0.f;
            const int kr = mf * 16 + l15;
            const short8 ka0 = *(const short8*)(Kc + kr * 64 + ((0 * 4 + l4) ^ (kr & 7)) * 8);
            const short8 ka1 = *(const short8*)(Kc + kr * 64 + ((1 * 4 + l4) ^ (kr & 7)) * 8);
            acc_s[mf] = __builtin_amdgcn_mfma_f32_16x16x32_bf16(ka0, qf0, acc_s[mf], 0, 0, 0);
            acc_s[mf] = __builtin_amdgcn_mfma_f32_16x16x32_bf16(ka1, qf1, acc_s[mf], 0, 0, 0);
        }
        float sv[16];
#pragma unroll
        for (int mf = 0; mf < 4; ++mf)
#pragma unroll
            for (int r = 0; r < 4; ++r) sv[mf * 4 + r] = SCALE * acc_s[mf][r];
        float pm = sv[0];
#pragma unroll
        for (int j = 1; j < 16; ++j) pm = fmaxf(pm, sv[j]);
        pm = fmaxf(pm, __shfl_xor(pm, 16, 64));
        pm = fmaxf(pm, __shfl_xor(pm, 32, 64));
        const float mnew = fmaxf(m, pm);
        const float corr = __expf(m - mnew);
        float rs = 0.f;
#pragma unroll
        for (int j = 0; j < 16; ++j) { sv[j] = __expf(sv[j] - mnew); rs += sv[j]; }
        rs += __shfl_xor(rs, 16, 64);
        rs += __shfl_xor(rs, 32, 64);
        lsum = lsum * corr + rs;
        m = mnew;
        const float cf0 = __shfl(corr, l4 * 4 + 0, 64);
        const float cf1 = __shfl(corr, l4 * 4 + 1, 64);
        const float cf2 = __shfl(corr, l4 * 4 + 2, 64);
        const float cf3 = __shfl(corr, l4 * 4 + 3, 64);
#pragma unroll
        for (int nf = 0; nf < 4; ++nf) {
            acc_o[nf][0] *= cf0; acc_o[nf][1] *= cf1;
            acc_o[nf][2] *= cf2; acc_o[nf][3] *= cf3;
        }
#pragma unroll
        for (int mf = 0; mf < 4; ++mf) {
            ushort4 pw;
            pw.x = f2bf(sv[mf * 4 + 0]); pw.y = f2bf(sv[mf * 4 + 1]);
            pw.z = f2bf(sv[mf * 4 + 2]); pw.w = f2bf(sv[mf * 4 + 3]);
            *(ushort4*)(myP + l15 * 72 + mf * 16 + l4 * 4) = pw;
        }
#pragma unroll
        for (int ks = 0; ks < 2; ++ks) {
            const short8 pa = *(const short8*)(myP + l15 * 72 + ks * 32 + l4 * 8);
#pragma unroll
            for (int nf = 0; nf < 4; ++nf) {
                const int dr = nf * 16 + l15;
                const short8 vb = *(const short8*)(Vc + dr * 64 + ((ks * 4 + l4) ^ (dr & 7)) * 8);
                acc_o[nf] = __builtin_amdgcn_mfma_f32_16x16x32_bf16(pa, vb, acc_o[nf], 0, 0, 0);
            }
        }
        __syncthreads();
        cur ^= 1;
    }

    // ---- write partials ----
    float* ob = oPart + (((long)sp * NH + h) * 8 + qt) * 4096;
#pragma unroll
    for (int nf = 0; nf < 4; ++nf)
#pragma unroll
        for (int r = 0; r < 4; ++r)
            ob[(wave * 16 + l4 * 4 + r) * 64 + nf * 16 + l15] = acc_o[nf][r];
    if (lane < 16) {
        const int qi = wave * 16 + lane;
        mPart[((sp * NH + h) * 8 + qt) * 64 + qi] = m;
        lPart[((sp * NH + h) * 8 + qt) * 64 + qi] = lsum;
    }

    // ---- last block for this (qt,h) combines all splits (release/acquire) ----
    __threadfence();
    if (t == 0) {
        const unsigned old = atomicAdd(&cnt[qt * NH + h], 1u);
        isLast = (old == NSPLIT - 1);
        if (old == NSPLIT - 1) cnt[qt * NH + h] = 0u;   // self-reset for next launch
    }
    __syncthreads();
    if (!isLast) return;
    __threadfence();

    const int q = t >> 2, d0 = (t & 3) << 4;
    float mi[NSPLIT], li[NSPLIT];
#pragma unroll
    for (int sp2 = 0; sp2 < NSPLIT; ++sp2) {
        const int sb = ((sp2 * NH + h) * 8 + qt) * 64 + q;
        mi[sp2] = mPart[sb];
        li[sp2] = lPart[sb];
    }
    float ms = 0.f;
#pragma unroll
    for (int sp2 = 0; sp2 < NSPLIT; ++sp2) ms = fmaxf(ms, mi[sp2]);
    float denom = ZCNT * __expf(-ms);
    float f[NSPLIT];
#pragma unroll
    for (int sp2 = 0; sp2 < NSPLIT; ++sp2) { f[sp2] = __expf(mi[sp2] - ms); denom += li[sp2] * f[sp2]; }
    const float inv = 1.f / denom;
    float o[16];
#pragma unroll
    for (int j = 0; j < 16; ++j) o[j] = 0.f;
#pragma unroll
    for (int sp2 = 0; sp2 < NSPLIT; ++sp2) {
        const float* ob2 = oPart + (((long)sp2 * NH + h) * 8 + qt) * 4096 + q * 64 + d0;
        const float fs = f[sp2] * inv;
#pragma unroll
        for (int j = 0; j < 16; j += 4) {
            const float4 v = *(const float4*)(ob2 + j);
            o[j] += fs * v.x; o[j + 1] += fs * v.y; o[j + 2] += fs * v.z; o[j + 3] += fs * v.w;
        }
    }
    u16* op = o_bf + (qt * 64 + q) * 512 + h * 64 + d0;
#pragma unroll
    for (int j = 0; j < 16; j += 4) {
        ushort4 w4;
        w4.x = f2bf(o[j]); w4.y = f2bf(o[j + 1]); w4.z = f2bf(o[j + 2]); w4.w = f2bf(o[j + 3]);
        *(ushort4*)(op + j) = w4;
    }
}

// ---------- fused prologue: conversions + weight transposes + simenc/cnt zero ----------
#define PRO_DATA 8192
#define PRO_W4   1024
#define PRO_WKV  512
#define PRO_MEM  256
#define PRO_SIM  16
#define PRO_CNT  1
__global__ __launch_bounds__(256)
void prologue(const float* __restrict__ data, const float* __restrict__ Memory,
              const float* __restrict__ Wkv, const float* __restrict__ Wq,
              const float* __restrict__ Wm,
              u16* __restrict__ data_bf, u16* __restrict__ Mbf,
              u16* __restrict__ WkvT, u16* __restrict__ WqT, u16* __restrict__ WmT,
              unsigned* __restrict__ simenc, unsigned* __restrict__ cnt)
{
    __shared__ float tile[32][33];
    const int bid = blockIdx.x, t = threadIdx.x;
    if (bid < PRO_DATA) {                      // data f32 -> bf16
        const int i = (bid * 256 + t) * 4;
        const float4 v = *(const float4*)(data + i);
        ushort4 o;
        o.x = f2bf(v.x); o.y = f2bf(v.y); o.z = f2bf(v.z); o.w = f2bf(v.w);
        *(ushort4*)(data_bf + i) = o;
        return;
    }
    int b2 = bid - PRO_DATA;
    const int tx = t & 31, ty = t >> 5;
    if (b2 < PRO_W4) {                         // Wq/Wm transposes (512x512 x4)
        const int z = b2 >> 8, q = b2 & 255;
        const float* S = (z < 2) ? (Wq + (long)z * DIM * DIM) : (Wm + (long)(z - 2) * DIM * DIM);
        u16* D = (z < 2) ? (WqT + (long)z * DIM * DIM) : (WmT + (long)(z - 2) * DIM * DIM);
        const int c0 = (q & 15) * 32, r0 = (q >> 4) * 32;
#pragma unroll
        for (int j = 0; j < 32; j += 8)
            tile[ty + j][tx] = S[(long)(r0 + ty + j) * DIM + c0 + tx];
        __syncthreads();
#pragma unroll
        for (int j = 0; j < 32; j += 8)
            D[(long)(c0 + ty + j) * DIM + r0 + tx] = f2bf(tile[tx][ty + j]);
        return;
    }
    b2 -= PRO_W4;
    if (b2 < PRO_WKV) {                        // Wkv [512][1024] -> WkvT [1024][512]
        const int c0 = (b2 & 31) * 32, r0 = (b2 >> 5) * 32;
#pragma unroll
        for (int j = 0; j < 32; j += 8)
            tile[ty + j][tx] = Wkv[(long)(r0 + ty + j) * KVDIM + c0 + tx];
        __syncthreads();
#pragma unroll
        for (int j = 0; j < 32; j += 8)
            WkvT[(long)(c0 + ty + j) * DIM + r0 + tx] = f2bf(tile[tx][ty + j]);
        return;
    }
    b2 -= PRO_WKV;
    if (b2 < PRO_MEM) {                        // Memory f32 -> bf16
        const int i = (b2 * 256 + t) * 4;
        const float4 v = *(const float4*)(Memory + i);
        ushort4 o;
        o.x = f2bf(v.x); o.y = f2bf(v.y); o.z = f2bf(v.z); o.w = f2bf(v.w);
        *(ushort4*)(Mbf + i) = o;
        return;
    }
    b2 -= PRO_MEM;
    if (b2 < PRO_SIM) {                        // zero simenc (16 blocks)
        const int i = (b2 * 256 + t) * 4;
        uint4 z; z.x = z.y = z.z = z.w = 0u;
        *(uint4*)(simenc + i) = z;
        return;
    }
    // zero split counters (64 entries, padded to 256)
    if (t < 64) cnt[t] = 0u;
}

// ---------- exclusive scan across 1024 threads ----------
__device__ __forceinline__ unsigned scan1024_excl(unsigned v, unsigned* wsum)
{
    const int lane = threadIdx.x & 63, wv = threadIdx.x >> 6;
    __syncthreads();
    unsigned x = v;
#pragma unroll
    for (int o = 1; o < 64; o <<= 1) {
        unsigned y = __shfl_up(x, o, 64);
        if (lane >= o) x += y;
    }
    if (lane == 63) wsum[wv] = x;
    __syncthreads();
    if (threadIdx.x < 16) {
        unsigned w2 = wsum[threadIdx.x];
#pragma unroll
        for (int o = 1; o < 16; o <<= 1) {
            unsigned y = __shfl_up(w2, o, 64);
            if ((int)threadIdx.x >= o) w2 += y;
        }
        wsum[threadIdx.x] = w2;
    }
    __syncthreads();
    const unsigned off = (wv > 0) ? wsum[wv - 1] : 0u;
    return off + x - v;
}

// ---------- clustered per-wave histogram add (for concentrated distributions) ----------
__device__ __forceinline__ void clustered_add(unsigned* hist, unsigned bin)
{
    bool pending = true;
    while (__any(pending)) {
        const unsigned long long mk = __ballot(pending);
        const int lead = (int)__ffsll(mk) - 1;
        const unsigned lbin = (unsigned)__shfl((int)bin, lead, 64);
        const unsigned long long same = __ballot(pending && (bin == lbin));
        if ((int)(threadIdx.x & 63) == lead)
            atomicAdd(&hist[lbin], (unsigned)__popcll(same));
        if (bin == lbin) pending = false;
    }
}

// ---------- exact top-k via radix select (hybrid: clustered pass-3, private passes 2-0) ----------
#define SEL_T 1024
#define SEL_CH (N_DATA / SEL_T)
__global__ __launch_bounds__(SEL_T)
void select_topk(const unsigned* __restrict__ key, int* __restrict__ idxo, int k)
{
    __shared__ unsigned whist[16][256];
    __shared__ unsigned hist[256];
    __shared__ unsigned wsum[16];
    __shared__ unsigned sh_bin, sh_r;
    const int t = threadIdx.x;
    const int wv = t >> 6;
    const int base = t * SEL_CH;

    unsigned kreg[SEL_CH];
    {
        const uint4* kp = (const uint4*)(key + base);
#pragma unroll
        for (int q = 0; q < SEL_CH / 4; ++q) {
            const uint4 v = kp[q];
            kreg[q * 4 + 0] = v.x; kreg[q * 4 + 1] = v.y;
            kreg[q * 4 + 2] = v.z; kreg[q * 4 + 3] = v.w;
        }
    }

    unsigned prefix = 0, mask = 0;
    unsigned r = (unsigned)k;
    for (int p = 3; p >= 0; --p) {
        __syncthreads();
        if (p == 3) {
            if (t < 256) hist[t] = 0u;
            __syncthreads();
#pragma unroll
            for (int c = 0; c < SEL_CH; ++c)
                clustered_add(hist, kreg[c] >> 24);
        } else {
            for (int i = t; i < 16 * 256; i += SEL_T) ((unsigned*)whist)[i] = 0u;
            __syncthreads();
#pragma unroll
            for (int c = 0; c < SEL_CH; ++c) {
                const unsigned kv = kreg[c];
                if ((kv & mask) == prefix)
                    atomicAdd(&whist[wv][(kv >> (p * 8)) & 255u], 1u);
            }
            __syncthreads();
            if (t < 256) {
                unsigned s = 0;
#pragma unroll
                for (int wq = 0; wq < 16; ++wq) s += whist[wq][t];
                hist[t] = s;
            }
        }
        __syncthreads();
        if (t < 64) {
            const int b0 = 255 - 4 * t;
            const unsigned c = hist[b0] + hist[b0 - 1] + hist[b0 - 2] + hist[b0 - 3];
            unsigned x = c;
#pragma unroll
            for (int o = 1; o < 64; o <<= 1) {
                unsigned y = __shfl_up(x, o, 64);
                if (t >= o) x += y;
            }
            const unsigned pre = x - c;
            if (pre < r && r <= x) {
                unsigned cum = pre;
#pragma unroll
                for (int j = 0; j < 4; ++j) {
                    const int b = b0 - j;
                    cum += hist[b];
                    if (cum >= r) { sh_bin = (unsigned)b; sh_r = r - (cum - hist[b]); break; }
                }
            }
        }
        __syncthreads();
        prefix |= sh_bin << (p * 8);
        mask |= 255u << (p * 8);
        r = sh_r;
    }
    const unsigned thr = prefix;
    const unsigned ties = r;

    unsigned ceq = 0;
#pragma unroll
    for (int c = 0; c < SEL_CH; ++c) ceq += (kreg[c] == thr) ? 1u : 0u;
    const unsigned eqbase = scan1024_excl(ceq, wsum);
    unsigned eq = eqbase, csel = 0;
#pragma unroll
    for (int c = 0; c < SEL_CH; ++c) {
        const unsigned kv = kreg[c];
        bool s;
        if (kv == thr) { s = (eq < ties); ++eq; }
        else s = (kv > thr);
        csel += s ? 1u : 0u;
    }
    unsigned pos = scan1024_excl(csel, wsum);
    eq = eqbase;
#pragma unroll
    for (int c = 0; c < SEL_CH; ++c) {
        const unsigned kv = kreg[c];
        bool s;
        if (kv == thr) { s = (eq < ties); ++eq; }
        else s = (kv > thr);
        if (s) idxo[pos++] = base + c;
    }
}

// ---------- host orchestration ----------
extern "C" void kernel_launch(void* const* d_in, const int* in_sizes, int n_in,
                              void* d_out, int out_size, void* d_ws, size_t ws_size,
                              hipStream_t stream)
{
    (void)in_sizes; (void)n_in; (void)out_size; (void)ws_size;
    const float* data   = (const float*)d_in[0];
    const float* Memory = (const float*)d_in[1];
    const float* Wkv    = (const float*)d_in[2];
    const float* Wq     = (const float*)d_in[3];
    const float* Wm     = (const float*)d_in[4];
    const float* bm     = (const float*)d_in[5];
    float* out = (float*)d_out;

    char* w = (char*)d_ws;
    unsigned* simenc = (unsigned*)(w + 0);             // 64K
    int*   idx     = (int*)  (w + 65536);              // 16K
    float* lse     = (float*)(w + 81920);              // 64K
    float* mlp     = (float*)(w + 147456);             // 64K
    float* Ma      = (float*)(w + 262144);             // 1M
    float* Mb      = (float*)(w + 1310720);            // 1M
    u16*   Mbf0    = (u16*)  (w + 2359296);            // 512K
    u16*   MT_bf   = (u16*)  (w + 2883584);            // 512K
    u16*   WqT_bf  = (u16*)  (w + 3407872);            // 1M (2 layers)
    u16*   WmT_bf  = (u16*)  (w + 4456448);            // 1M
    u16*   WkvT_bf = (u16*)  (w + 5505024);            // 1M
    u16*   o_bf    = (u16*)  (w + 7077888);            // 512K
    u16*   data_bf = (u16*)  (w + 8650752);            // 16M
    u16*   kvsel_bf= (u16*)  (w + 25427968);           // 8M  [4096][1024] (K half used)
    u16*   vT_bf   = (u16*)  (w + 33816576);           // 4M  [8*64][4096]
    float* oPart   = (float*)(w + 38010880);           // 4M
    float* mPart   = (float*)(w + 42205184);           // 64K
    float* lPart   = (float*)(w + 42270720);           // 64K
    unsigned* spCnt = (unsigned*)(w + 42336256);       // 1K  (64 counters)
    u16*   logits_bf = (u16*)(w + 54788096);           // 16M [16384][512] (p)
    u16*   Mbfa    = (u16*)  (w + 88342528);           // 512K
    u16*   Mbfb    = (u16*)  (w + 88866816);           // 512K

    // fused prologue (1 dispatch): conversions + transposes + simenc/cnt zero
    prologue<<<PRO_DATA + PRO_W4 + PRO_WKV + PRO_MEM + PRO_SIM + PRO_CNT, 256, 0, stream>>>(
        data, Memory, Wkv, Wq, Wm, data_bf, Mbf0, WkvT_bf, WqT_bf, WmT_bf, simenc, spCnt);

    auto sim_select_kv = [&](const u16* Mrows_bf) {
        mfma_gemm<2, 2, false, 2, false, false><<<dim3(128, 4, 1), 256, 0, stream>>>(
            data_bf, Mrows_bf, nullptr, nullptr, nullptr, simenc, nullptr,
            nullptr, nullptr, nullptr,
            DIM, DIM, DIM, 0, 0, 0, 0, 1, 0, SCALE);
        select_topk<<<1, SEL_T, 0, stream>>>(simenc, idx, KSEL);
        mfma_gemm<2, 2, true, 3, false, false><<<dim3(32, 8, 1), 256, 0, stream>>>(
            data_bf, WkvT_bf, nullptr, idx, kvsel_bf, nullptr, vT_bf,
            nullptr, nullptr, nullptr,
            DIM, DIM, DIM, KVDIM, 0, 0, 0, 1, 0, 1.0f);
    };

    auto cross = [&](const float* Mcur, const u16* Mcur_bf, float* Mnext, u16* Mnext_bf,
                     int l, u16* MTout) {
        // flash attention with fused q-proj and last-block split-K combine
        flash_att<<<dim3(8, NH, NSPLIT), 256, 0, stream>>>(
            Mcur_bf, WqT_bf + (long)l * DIM * DIM, kvsel_bf, vT_bf,
            oPart, mPart, lPart, o_bf, spCnt);
        // Wm GEMM + bias + residual + LayerNorm fused (32 blocks); zeroes simenc
        wmln<<<32, 512, 0, stream>>>(
            o_bf, WmT_bf + (long)l * DIM * DIM, bm + (long)l * DIM, Mcur,
            Mnext, Mnext_bf, simenc, MTout);
    };

    const float* Mcur = Memory;
    const u16*  curbf = Mbf0;
    float* Mnext = Ma;
    u16*   nextbf = Mbfa;
    sim_select_kv(curbf);
    for (int it = 0; it < 2; ++it) {
        for (int l = 0; l < 2; ++l) {
            const bool last = (it == 1 && l == 1);
            cross(Mcur, curbf, Mnext, nextbf, l, last ? MT_bf : nullptr);
            Mcur = Mnext; curbf = nextbf;
            Mnext = (Mcur == Ma) ? Mb : Ma;
            nextbf = (curbf == Mbfa) ? Mbfb : Mbfa;
        }
        if (it == 0) sim_select_kv(curbf);
    }

    // final: fused logits+softmax (p -> logits_bf), then p@M with fused loss reduction
    mfma_gemm_sm<<<N_DATA / 64, 512, 0, stream>>>(
        data_bf, curbf, logits_bf, out, lse, mlp, SCALE);
    mfma_gemm<2, 2, false, 0, false, true><<<dim3(128, 4, 1), 256, 0, stream>>>(
        logits_bf, MT_bf, nullptr, nullptr, out + N_DATA, nullptr, nullptr,
        lse, mlp, out + N_DATA + (long)N_DATA * DIM,
        MEM, MEM, MEM, DIM, 0, 0, 0, 1, 0, 1.0f);
}

// Round 14
// 375.113 us; speedup vs baseline: 1.2950x; 1.2950x over previous
//
#include <hip/hip_runtime.h>
#include <cstdint>

#define N_DATA 16384
#define DIM 512
#define MEM 512
#define KSEL 4096
#define NH 8
#define DH 64
#define KVDIM 1024
#define SCALE 0.125f
#define ZCNT 12288.0f
#define LN_EPS 1e-5f
#define NSPLIT 4
#define ROWS_SP (KSEL / NSPLIT)

typedef unsigned short u16;
using short8 = __attribute__((ext_vector_type(8))) short;
using f32x4  = __attribute__((ext_vector_type(4))) float;

// ---------- scalar helpers ----------
__device__ __forceinline__ unsigned fenc(float x) {
    unsigned u = __float_as_uint(x);
    return (u & 0x80000000u) ? ~u : (u | 0x80000000u);
}
__device__ __forceinline__ u16 f2bf(float x) {          // RNE f32 -> bf16
    unsigned u = __float_as_uint(x);
    u += 0x7fffu + ((u >> 16) & 1u);
    return (u16)(u >> 16);
}
__device__ __forceinline__ float bf2f(u16 h) { return __uint_as_float(((unsigned)h) << 16); }

__device__ __forceinline__ float waveSum(float v) {
#pragma unroll
    for (int o = 32; o > 0; o >>= 1) v += __shfl_down(v, o, 64);
    return v;
}
// blockDim.x == 256 assumed (4 waves)
__device__ float blockSum(float v) {
    __shared__ float sh[4];
    __syncthreads();
    v = waveSum(v);
    if ((threadIdx.x & 63) == 0) sh[threadIdx.x >> 6] = v;
    __syncthreads();
    if (threadIdx.x == 0) { float s = sh[0]; for (int i = 1; i < 4; ++i) s += sh[i]; sh[0] = s; }
    __syncthreads();
    return sh[0];
}

// ---------- global -> LDS async staging of a ROWS x 32 bf16 tile ----------
template<int ROWS, int NW, bool GATHER>
__device__ __forceinline__ void stage_tile(const u16* __restrict__ src, int ld, int k0,
                                           int row0, const int* __restrict__ gidx,
                                           u16* lds, int wave)
{
    constexpr int NI = ROWS / 16;
    const int lane = threadIdx.x & 63;
#pragma unroll
    for (int i = wave; i < NI; i += NW) {
        const int ch = i * 64 + lane;
        const int r = ch >> 2, cc = ch & 3;
        int rg = row0 + r;
        if (GATHER) rg = gidx[rg];
        const u16* g = src + (long)rg * ld + k0 + cc * 8;
        u16* l = lds + i * 512;
        __builtin_amdgcn_global_load_lds((const __attribute__((address_space(1))) void*)g,
                                         (__attribute__((address_space(3))) void*)l,
                                         16, 0, 0);
    }
}

// ---------- bf16 MFMA GEMM (BK=32): C = alpha*A*B^T ----------
// EPI: 0 = store fp32, 1 = store bf16, 2 = rowmax atomic into simenc,
//      3 = kv split: K-half (bn0<512) -> C[ldc=1024]; V-half -> vTo transposed
// LOSS: block (0,0) additionally reduces lse/mlp scalars into o2 after its store
template<int WM, int WN, bool GATHER, int EPI, bool BIAS, bool LOSS>
__global__ __launch_bounds__(WM * WN * 64)
void mfma_gemm(const u16* __restrict__ A, const u16* __restrict__ B,
               const float* __restrict__ bias, const int* __restrict__ gidx,
               void* __restrict__ Cv, unsigned* __restrict__ simenc,
               u16* __restrict__ vTo,
               const float* __restrict__ lseIn, const float* __restrict__ mlpIn,
               float* __restrict__ o2,
               int K, int lda, int ldb, int ldc,
               long zsA, long zsB, long zsC, int zdiv, long zsplitC, float alpha)
{
    constexpr int BM = WM * 64, BN = WN * 64, NW = WM * WN;
    __shared__ __align__(16) u16 As[BM * 32];
    __shared__ __align__(16) u16 Bs[BN * 32];

    const int t = threadIdx.x;
    const int wave = t >> 6, lane = t & 63;
    const int wr = wave / WN, wc = wave % WN;
    const int l15 = lane & 15, l4 = lane >> 4;
    const int bm0 = blockIdx.x * BM, bn0 = blockIdx.y * BN;
    const int zs = (int)blockIdx.z % zdiv;
    const int zh = (int)blockIdx.z / zdiv;
    A += (long)zh * zsA;
    B += (long)zh * zsB;

    f32x4 acc[4][4];
#pragma unroll
    for (int i = 0; i < 4; ++i)
#pragma unroll
        for (int j = 0; j < 4; ++j)
#pragma unroll
            for (int r = 0; r < 4; ++r) acc[i][j][r] = 0.f;

    const int Kd = K / zdiv;
    const int kbeg = zs * Kd;
    for (int k0 = kbeg; k0 < kbeg + Kd; k0 += 32) {
        stage_tile<BM, NW, GATHER>(A, lda, k0, bm0, gidx, As, wave);
        stage_tile<BN, NW, false>(B, ldb, k0, bn0, nullptr, Bs, wave);
        __syncthreads();
        short8 a[4], b[4];
#pragma unroll
        for (int fm = 0; fm < 4; ++fm)
            a[fm] = *(const short8*)(As + (wr * 64 + fm * 16 + l15) * 32 + l4 * 8);
#pragma unroll
        for (int fn = 0; fn < 4; ++fn)
            b[fn] = *(const short8*)(Bs + (wc * 64 + fn * 16 + l15) * 32 + l4 * 8);
#pragma unroll
        for (int fm = 0; fm < 4; ++fm)
#pragma unroll
            for (int fn = 0; fn < 4; ++fn)
                acc[fm][fn] = __builtin_amdgcn_mfma_f32_16x16x32_bf16(a[fm], b[fn], acc[fm][fn], 0, 0, 0);
        __syncthreads();
    }

    if (EPI == 2) {
#pragma unroll
        for (int fm = 0; fm < 4; ++fm)
#pragma unroll
            for (int r = 0; r < 4; ++r) {
                float mx = acc[fm][0][r];
#pragma unroll
                for (int fn = 1; fn < 4; ++fn) mx = fmaxf(mx, acc[fm][fn][r]);
#pragma unroll
                for (int o = 8; o >= 1; o >>= 1) mx = fmaxf(mx, __shfl_xor(mx, o, 64));
                if (l15 == 0) {
                    const int row = bm0 + wr * 64 + fm * 16 + l4 * 4 + r;
                    atomicMax(simenc + row, fenc(alpha * mx));
                }
            }
    } else if (EPI == 0) {
        float* C = (float*)Cv + (long)zh * zsC + (long)zs * zsplitC;
#pragma unroll
        for (int fm = 0; fm < 4; ++fm)
#pragma unroll
            for (int fn = 0; fn < 4; ++fn)
#pragma unroll
                for (int r = 0; r < 4; ++r) {
                    const int row = bm0 + wr * 64 + fm * 16 + l4 * 4 + r;
                    const int col = bn0 + wc * 64 + fn * 16 + l15;
                    float v = alpha * acc[fm][fn][r];
                    if (BIAS) v += bias[col];
                    C[(long)row * ldc + col] = v;
                }
    } else if (EPI == 1) {
        u16* C = (u16*)Cv + (long)zh * zsC + (long)zs * zsplitC;
#pragma unroll
        for (int fm = 0; fm < 4; ++fm)
#pragma unroll
            for (int fn = 0; fn < 4; ++fn)
#pragma unroll
                for (int r = 0; r < 4; ++r) {
                    const int row = bm0 + wr * 64 + fm * 16 + l4 * 4 + r;
                    const int col = bn0 + wc * 64 + fn * 16 + l15;
                    float v = alpha * acc[fm][fn][r];
                    if (BIAS) v += bias[col];
                    C[(long)row * ldc + col] = f2bf(v);
                }
    } else {   // EPI == 3: kv projection split write
        if (bn0 < 512) {        // K half -> kvsel rows (ld 1024)
            u16* C = (u16*)Cv;
#pragma unroll
            for (int fm = 0; fm < 4; ++fm)
#pragma unroll
                for (int fn = 0; fn < 4; ++fn)
#pragma unroll
                    for (int r = 0; r < 4; ++r) {
                        const int row = bm0 + wr * 64 + fm * 16 + l4 * 4 + r;
                        const int col = bn0 + wc * 64 + fn * 16 + l15;
                        C[(long)row * ldc + col] = f2bf(alpha * acc[fm][fn][r]);
                    }
        } else {                // V half -> vTo[d][j] transposed (ld 4096)
#pragma unroll
            for (int fm = 0; fm < 4; ++fm)
#pragma unroll
                for (int fn = 0; fn < 4; ++fn) {
                    const int d = bn0 + wc * 64 + fn * 16 + l15 - 512;
                    const int row0 = bm0 + wr * 64 + fm * 16 + l4 * 4;
                    ushort4 pw;
                    pw.x = f2bf(alpha * acc[fm][fn][0]);
                    pw.y = f2bf(alpha * acc[fm][fn][1]);
                    pw.z = f2bf(alpha * acc[fm][fn][2]);
                    pw.w = f2bf(alpha * acc[fm][fn][3]);
                    *(ushort4*)(vTo + (long)d * 4096 + row0) = pw;
                }
        }
    }

    if (LOSS) {
        if (blockIdx.x == 0 && blockIdx.y == 0) {
            float s1 = 0.f, s2 = 0.f;
            for (int i = t; i < N_DATA; i += WM * WN * 64) {
                s1 += mlpIn[i];
                const float l = lseIn[i];
                s2 += l * l;
            }
            s1 = blockSum(s1);
            s2 = blockSum(s2);
            if (t == 0) { o2[0] = -s1 * (1.f / N_DATA); o2[1] = s2 * (1.f / N_DATA); }
        }
    }
}

// ---------- full-row GEMM (BM=64, BN=512, K=512) + fused log-softmax epilogue ----------
__global__ __launch_bounds__(512)
void mfma_gemm_sm(const u16* __restrict__ A, const u16* __restrict__ B,
                  u16* __restrict__ Obf, float* __restrict__ simf,
                  float* __restrict__ lse, float* __restrict__ mlp, float alpha)
{
    __shared__ __align__(16) u16 As[64 * 32];     // 4KB
    __shared__ __align__(16) u16 Bs[512 * 32];    // 32KB
    const int t = threadIdx.x, wave = t >> 6, lane = t & 63;
    const int wc = wave;
    const int l15 = lane & 15, l4 = lane >> 4;
    const int bm0 = blockIdx.x * 64;

    f32x4 acc[4][4];
#pragma unroll
    for (int i = 0; i < 4; ++i)
#pragma unroll
        for (int j = 0; j < 4; ++j)
#pragma unroll
            for (int r = 0; r < 4; ++r) acc[i][j][r] = 0.f;

    for (int k0 = 0; k0 < 512; k0 += 32) {
        stage_tile<64, 8, false>(A, 512, k0, bm0, nullptr, As, wave);
        stage_tile<512, 8, false>(B, 512, k0, 0, nullptr, Bs, wave);
        __syncthreads();
        short8 a[4], b[4];
#pragma unroll
        for (int fm = 0; fm < 4; ++fm)
            a[fm] = *(const short8*)(As + (fm * 16 + l15) * 32 + l4 * 8);
#pragma unroll
        for (int fn = 0; fn < 4; ++fn)
            b[fn] = *(const short8*)(Bs + (wc * 64 + fn * 16 + l15) * 32 + l4 * 8);
#pragma unroll
        for (int fm = 0; fm < 4; ++fm)
#pragma unroll
            for (int fn = 0; fn < 4; ++fn)
                acc[fm][fn] = __builtin_amdgcn_mfma_f32_16x16x32_bf16(a[fm], b[fn], acc[fm][fn], 0, 0, 0);
        __syncthreads();
    }

    float* red  = (float*)As;          // [64][8]
    float* rowv = (float*)Bs;          // [64] m + [64] l

#pragma unroll
    for (int fm = 0; fm < 4; ++fm)
#pragma unroll
        for (int r = 0; r < 4; ++r) {
            float mx = alpha * acc[fm][0][r];
#pragma unroll
            for (int fn = 1; fn < 4; ++fn) mx = fmaxf(mx, alpha * acc[fm][fn][r]);
#pragma unroll
            for (int o = 1; o <= 8; o <<= 1) mx = fmaxf(mx, __shfl_xor(mx, o, 64));
            if (l15 == 0) red[(fm * 16 + l4 * 4 + r) * 8 + wc] = mx;
        }
    __syncthreads();
    if (t < 64) {
        float mx = red[t * 8];
#pragma unroll
        for (int j = 1; j < 8; ++j) mx = fmaxf(mx, red[t * 8 + j]);
        rowv[t] = mx;
    }
    __syncthreads();
#pragma unroll
    for (int fm = 0; fm < 4; ++fm)
#pragma unroll
        for (int r = 0; r < 4; ++r) {
            const int rl = fm * 16 + l4 * 4 + r;
            const float m = rowv[rl];
            float s = 0.f;
#pragma unroll
            for (int fn = 0; fn < 4; ++fn) s += __expf(alpha * acc[fm][fn][r] - m);
#pragma unroll
            for (int o = 1; o <= 8; o <<= 1) s += __shfl_xor(s, o, 64);
            if (l15 == 0) red[rl * 8 + wc] = s;
        }
    __syncthreads();
    if (t < 64) {
        float s = 0.f;
#pragma unroll
        for (int j = 0; j < 8; ++j) s += red[t * 8 + j];
        const float m = rowv[t];
        const float l = m + __logf(s);
        const int gr = bm0 + t;
        simf[gr] = m; lse[gr] = l; mlp[gr] = m - l;
        rowv[64 + t] = l;
    }
    __syncthreads();
#pragma unroll
    for (int fm = 0; fm < 4; ++fm)
#pragma unroll
        for (int r = 0; r < 4; ++r) {
            const int rl = fm * 16 + l4 * 4 + r;
            const float l = rowv[64 + rl];
#pragma unroll
            for (int fn = 0; fn < 4; ++fn) {
                const int col = wc * 64 + fn * 16 + l15;
                Obf[(long)(bm0 + rl) * 512 + col] = f2bf(__expf(alpha * acc[fm][fn][r] - l));
            }
        }
}

// ---------- Wm GEMM + bias + residual + LayerNorm, full-row BM=16 (32 blocks) ----------
// also zeroes simenc; optionally writes M^T bf16 (last layer)
__global__ __launch_bounds__(512)
void wmln(const u16* __restrict__ A, const u16* __restrict__ BT,
          const float* __restrict__ bias, const float* __restrict__ Min,
          float* __restrict__ Mout, u16* __restrict__ Mbf,
          unsigned* __restrict__ simz, u16* __restrict__ MTout)
{
    __shared__ __align__(16) u16 As[16 * 32];      // 1KB
    __shared__ __align__(16) u16 Bs[512 * 32];     // 32KB
    __shared__ float red[16][8], red2[16][8], rowv[32];
    const int t = threadIdx.x, wave = t >> 6, lane = t & 63;
    const int wc = wave;
    const int l15 = lane & 15, l4 = lane >> 4;
    const int bm0 = blockIdx.x * 16;

    simz[blockIdx.x * 512 + t] = 0u;   // 32*512 == 16384

    f32x4 acc[4];
#pragma unroll
    for (int fn = 0; fn < 4; ++fn)
#pragma unroll
        for (int r = 0; r < 4; ++r) acc[fn][r] = 0.f;

    for (int k0 = 0; k0 < 512; k0 += 32) {
        stage_tile<16, 8, false>(A, 512, k0, bm0, nullptr, As, wave);
        stage_tile<512, 8, false>(BT, 512, k0, 0, nullptr, Bs, wave);
        __syncthreads();
        const short8 a = *(const short8*)(As + l15 * 32 + l4 * 8);
#pragma unroll
        for (int fn = 0; fn < 4; ++fn) {
            const short8 b = *(const short8*)(Bs + (wc * 64 + fn * 16 + l15) * 32 + l4 * 8);
            acc[fn] = __builtin_amdgcn_mfma_f32_16x16x32_bf16(a, b, acc[fn], 0, 0, 0);
        }
        __syncthreads();
    }

    float v[4][4];
#pragma unroll
    for (int fn = 0; fn < 4; ++fn) {
        const int col = wc * 64 + fn * 16 + l15;
        const float bi = bias[col];
#pragma unroll
        for (int r = 0; r < 4; ++r) {
            const int row = bm0 + l4 * 4 + r;
            v[fn][r] = acc[fn][r] + bi + Min[(long)row * 512 + col];
        }
    }
#pragma unroll
    for (int r = 0; r < 4; ++r) {
        float s = 0.f, s2 = 0.f;
#pragma unroll
        for (int fn = 0; fn < 4; ++fn) { const float x = v[fn][r]; s += x; s2 += x * x; }
#pragma unroll
        for (int o = 1; o <= 8; o <<= 1) { s += __shfl_xor(s, o, 64); s2 += __shfl_xor(s2, o, 64); }
        if (l15 == 0) { red[l4 * 4 + r][wc] = s; red2[l4 * 4 + r][wc] = s2; }
    }
    __syncthreads();
    if (t < 16) {
        float s = 0.f, s2 = 0.f;
#pragma unroll
        for (int j = 0; j < 8; ++j) { s += red[t][j]; s2 += red2[t][j]; }
        const float mu = s * (1.f / 512.f);
        const float var = s2 * (1.f / 512.f) - mu * mu;
        rowv[t] = mu;
        rowv[16 + t] = rsqrtf(var + LN_EPS);
    }
    __syncthreads();
#pragma unroll
    for (int fn = 0; fn < 4; ++fn) {
        const int col = wc * 64 + fn * 16 + l15;
#pragma unroll
        for (int r = 0; r < 4; ++r) {
            const int rl = l4 * 4 + r;
            const float y = (v[fn][r] - rowv[rl]) * rowv[16 + rl];
            Mout[(long)(bm0 + rl) * 512 + col] = y;
            Mbf [(long)(bm0 + rl) * 512 + col] = f2bf(y);
            if (MTout) MTout[(long)col * 512 + (bm0 + rl)] = f2bf(y);
        }
    }
}

// ---------- fused flash attention (q-proj fused, double-buffered K/V) ----------
__global__ __launch_bounds__(256)
void flash_att(const u16* __restrict__ Mbf, const u16* __restrict__ WqT,
               const u16* __restrict__ KV, const u16* __restrict__ VT,
               float* __restrict__ oPart, float* __restrict__ mPart,
               float* __restrict__ lPart)
{
    __shared__ __align__(16) u16 Qs[64 * 64];
    __shared__ __align__(16) u16 Ks[2][64 * 64];
    __shared__ __align__(16) u16 Vs[2][64 * 64];
    __shared__ __align__(16) u16 Ps[4][16 * 72];

    const int qt = blockIdx.x, h = blockIdx.y, sp = blockIdx.z;
    const int t = threadIdx.x, wave = t >> 6, lane = t & 63;
    const int l15 = lane & 15, l4 = lane >> 4;

    const u16* Kg = KV + ((long)sp * ROWS_SP) * 1024 + h * 64;
    const u16* Vg = VT + ((long)h * 64) * 4096 + sp * ROWS_SP;

    auto stageKV = [&](int kt, int buf) {
        const u16* Kt = Kg + (long)(kt * 64) * 1024;
        const u16* Vt = Vg + kt * 64;
#pragma unroll
        for (int i = wave; i < 8; i += 4) {
            const int ch = i * 64 + lane, r = ch >> 3, s = ch & 7;
            __builtin_amdgcn_global_load_lds(
                (const __attribute__((address_space(1))) void*)(Kt + (long)r * 1024 + ((s ^ (r & 7)) * 8)),
                (__attribute__((address_space(3))) void*)(Ks[buf] + i * 512), 16, 0, 0);
        }
#pragma unroll
        for (int i = wave; i < 8; i += 4) {
            const int ch = i * 64 + lane, r = ch >> 3, s = ch & 7;
            __builtin_amdgcn_global_load_lds(
                (const __attribute__((address_space(1))) void*)(Vt + (long)r * 4096 + ((s ^ (r & 7)) * 8)),
                (__attribute__((address_space(3))) void*)(Vs[buf] + i * 512), 16, 0, 0);
        }
    };

    stageKV(0, 0);

    // q-projection in registers
    f32x4 accq[4];
#pragma unroll
    for (int fn = 0; fn < 4; ++fn)
#pragma unroll
        for (int r = 0; r < 4; ++r) accq[fn][r] = 0.f;
    {
        const u16* Ag = Mbf + (long)(qt * 64 + wave * 16 + l15) * 512 + l4 * 8;
        const u16* Bg = WqT + (long)(h * 64 + l15) * 512 + l4 * 8;
#pragma unroll 4
        for (int k0 = 0; k0 < 512; k0 += 32) {
            const short8 a = *(const short8*)(Ag + k0);
#pragma unroll
            for (int fn = 0; fn < 4; ++fn) {
                const short8 b = *(const short8*)(Bg + (long)fn * 16 * 512 + k0);
                accq[fn] = __builtin_amdgcn_mfma_f32_16x16x32_bf16(a, b, accq[fn], 0, 0, 0);
            }
        }
    }
#pragma unroll
    for (int fn = 0; fn < 4; ++fn)
#pragma unroll
        for (int r = 0; r < 4; ++r) {
            const int qrow = wave * 16 + l4 * 4 + r;
            const int col = fn * 16 + l15;
            Qs[qrow * 64 + (((col >> 3) ^ (qrow & 7)) << 3) + (col & 7)] = f2bf(accq[fn][r]);
        }
    __syncthreads();

    const int qr = wave * 16 + l15;
    short8 qf0 = *(const short8*)(Qs + qr * 64 + ((0 * 4 + l4) ^ (qr & 7)) * 8);
    short8 qf1 = *(const short8*)(Qs + qr * 64 + ((1 * 4 + l4) ^ (qr & 7)) * 8);

    float m = -3.0e38f, lsum = 0.f;
    f32x4 acc_o[4];
#pragma unroll
    for (int nf = 0; nf < 4; ++nf)
#pragma unroll
        for (int r = 0; r < 4; ++r) acc_o[nf][r] = 0.f;

    u16* myP = &Ps[wave][0];
    constexpr int NT = ROWS_SP / 64;
    int cur = 0;

    for (int kt = 0; kt < NT; ++kt) {
        if (kt + 1 < NT) stageKV(kt + 1, cur ^ 1);
        const u16* Kc = Ks[cur];
        const u16* Vc = Vs[cur];
        f32x4 acc_s[4];
#pragma unroll
        for (int mf = 0; mf < 4; ++mf) {
#pragma unroll
            for (int r = 0; r < 4; ++r) acc_s[mf][r] = 0.f;
            const int kr = mf * 16 + l15;
            const short8 ka0 = *(const short8*)(Kc + kr * 64 + ((0 * 4 + l4) ^ (kr & 7)) * 8);
            const short8 ka1 = *(const short8*)(Kc + kr * 64 + ((1 * 4 + l4) ^ (kr & 7)) * 8);
            acc_s[mf] = __builtin_amdgcn_mfma_f32_16x16x32_bf16(ka0, qf0, acc_s[mf], 0, 0, 0);
            acc_s[mf] = __builtin_amdgcn_mfma_f32_16x16x32_bf16(ka1, qf1, acc_s[mf], 0, 0, 0);
        }
        float sv[16];
#pragma unroll
        for (int mf = 0; mf < 4; ++mf)
#pragma unroll
            for (int r = 0; r < 4; ++r) sv[mf * 4 + r] = SCALE * acc_s[mf][r];
        float pm = sv[0];
#pragma unroll
        for (int j = 1; j < 16; ++j) pm = fmaxf(pm, sv[j]);
        pm = fmaxf(pm, __shfl_xor(pm, 16, 64));
        pm = fmaxf(pm, __shfl_xor(pm, 32, 64));
        const float mnew = fmaxf(m, pm);
        const float corr = __expf(m - mnew);
        float rs = 0.f;
#pragma unroll
        for (int j = 0; j < 16; ++j) { sv[j] = __expf(sv[j] - mnew); rs += sv[j]; }
        rs += __shfl_xor(rs, 16, 64);
        rs += __shfl_xor(rs, 32, 64);
        lsum = lsum * corr + rs;
        m = mnew;
        const float cf0 = __shfl(corr, l4 * 4 + 0, 64);
        const float cf1 = __shfl(corr, l4 * 4 + 1, 64);
        const float cf2 = __shfl(corr, l4 * 4 + 2, 64);
        const float cf3 = __shfl(corr, l4 * 4 + 3, 64);
#pragma unroll
        for (int nf = 0; nf < 4; ++nf) {
            acc_o[nf][0] *= cf0; acc_o[nf][1] *= cf1;
            acc_o[nf][2] *= cf2; acc_o[nf][3] *= cf3;
        }
#pragma unroll
        for (int mf = 0; mf < 4; ++mf) {
            ushort4 pw;
            pw.x = f2bf(sv[mf * 4 + 0]); pw.y = f2bf(sv[mf * 4 + 1]);
            pw.z = f2bf(sv[mf * 4 + 2]); pw.w = f2bf(sv[mf * 4 + 3]);
            *(ushort4*)(myP + l15 * 72 + mf * 16 + l4 * 4) = pw;
        }
#pragma unroll
        for (int ks = 0; ks < 2; ++ks) {
            const short8 pa = *(const short8*)(myP + l15 * 72 + ks * 32 + l4 * 8);
#pragma unroll
            for (int nf = 0; nf < 4; ++nf) {
                const int dr = nf * 16 + l15;
                const short8 vb = *(const short8*)(Vc + dr * 64 + ((ks * 4 + l4) ^ (dr & 7)) * 8);
                acc_o[nf] = __builtin_amdgcn_mfma_f32_16x16x32_bf16(pa, vb, acc_o[nf], 0, 0, 0);
            }
        }
        __syncthreads();
        cur ^= 1;
    }

    float* ob = oPart + (((long)sp * NH + h) * 8 + qt) * 4096;
#pragma unroll
    for (int nf = 0; nf < 4; ++nf)
#pragma unroll
        for (int r = 0; r < 4; ++r)
            ob[(wave * 16 + l4 * 4 + r) * 64 + nf * 16 + l15] = acc_o[nf][r];
    if (lane < 16) {
        const int qi = wave * 16 + lane;
        mPart[((sp * NH + h) * 8 + qt) * 64 + qi] = m;
        lPart[((sp * NH + h) * 8 + qt) * 64 + qi] = lsum;
    }
}

// ---------- merge kv-split partials + analytic zeros term -> o_bf ----------
__global__ __launch_bounds__(256)
void flash_combine(const float* __restrict__ oPart, const float* __restrict__ mPart,
                   const float* __restrict__ lPart, u16* __restrict__ o_bf)
{
    const int qt = blockIdx.x & 7, h = blockIdx.x >> 3;
    const int t = threadIdx.x;
    const int q = t >> 2, d0 = (t & 3) << 4;
    float mi[NSPLIT], li[NSPLIT];
#pragma unroll
    for (int sp = 0; sp < NSPLIT; ++sp) {
        const int sb = ((sp * NH + h) * 8 + qt) * 64 + q;
        mi[sp] = mPart[sb];
        li[sp] = lPart[sb];
    }
    float ms = 0.f;
#pragma unroll
    for (int sp = 0; sp < NSPLIT; ++sp) ms = fmaxf(ms, mi[sp]);
    float denom = ZCNT * __expf(-ms);
    float f[NSPLIT];
#pragma unroll
    for (int sp = 0; sp < NSPLIT; ++sp) { f[sp] = __expf(mi[sp] - ms); denom += li[sp] * f[sp]; }
    const float inv = 1.f / denom;
    float o[16];
#pragma unroll
    for (int j = 0; j < 16; ++j) o[j] = 0.f;
#pragma unroll
    for (int sp = 0; sp < NSPLIT; ++sp) {
        const float* ob = oPart + (((long)sp * NH + h) * 8 + qt) * 4096 + q * 64 + d0;
        const float fs = f[sp] * inv;
#pragma unroll
        for (int j = 0; j < 16; j += 4) {
            const float4 v = *(const float4*)(ob + j);
            o[j] += fs * v.x; o[j + 1] += fs * v.y; o[j + 2] += fs * v.z; o[j + 3] += fs * v.w;
        }
    }
    u16* op = o_bf + (qt * 64 + q) * 512 + h * 64 + d0;
#pragma unroll
    for (int j = 0; j < 16; j += 4) {
        ushort4 w4;
        w4.x = f2bf(o[j]); w4.y = f2bf(o[j + 1]); w4.z = f2bf(o[j + 2]); w4.w = f2bf(o[j + 3]);
        *(ushort4*)(op + j) = w4;
    }
}

// ---------- fused prologue: conversions + weight transposes + simenc zero ----------
#define PRO_DATA 8192
#define PRO_W4   1024
#define PRO_WKV  512
#define PRO_MEM  256
#define PRO_SIM  16
__global__ __launch_bounds__(256)
void prologue(const float* __restrict__ data, const float* __restrict__ Memory,
              const float* __restrict__ Wkv, const float* __restrict__ Wq,
              const float* __restrict__ Wm,
              u16* __restrict__ data_bf, u16* __restrict__ Mbf,
              u16* __restrict__ WkvT, u16* __restrict__ WqT, u16* __restrict__ WmT,
              unsigned* __restrict__ simenc)
{
    __shared__ float tile[32][33];
    const int bid = blockIdx.x, t = threadIdx.x;
    if (bid < PRO_DATA) {                      // data f32 -> bf16
        const int i = (bid * 256 + t) * 4;
        const float4 v = *(const float4*)(data + i);
        ushort4 o;
        o.x = f2bf(v.x); o.y = f2bf(v.y); o.z = f2bf(v.z); o.w = f2bf(v.w);
        *(ushort4*)(data_bf + i) = o;
        return;
    }
    int b2 = bid - PRO_DATA;
    const int tx = t & 31, ty = t >> 5;
    if (b2 < PRO_W4) {                         // Wq/Wm transposes (512x512 x4)
        const int z = b2 >> 8, q = b2 & 255;
        const float* S = (z < 2) ? (Wq + (long)z * DIM * DIM) : (Wm + (long)(z - 2) * DIM * DIM);
        u16* D = (z < 2) ? (WqT + (long)z * DIM * DIM) : (WmT + (long)(z - 2) * DIM * DIM);
        const int c0 = (q & 15) * 32, r0 = (q >> 4) * 32;
#pragma unroll
        for (int j = 0; j < 32; j += 8)
            tile[ty + j][tx] = S[(long)(r0 + ty + j) * DIM + c0 + tx];
        __syncthreads();
#pragma unroll
        for (int j = 0; j < 32; j += 8)
            D[(long)(c0 + ty + j) * DIM + r0 + tx] = f2bf(tile[tx][ty + j]);
        return;
    }
    b2 -= PRO_W4;
    if (b2 < PRO_WKV) {                        // Wkv [512][1024] -> WkvT [1024][512]
        const int c0 = (b2 & 31) * 32, r0 = (b2 >> 5) * 32;
#pragma unroll
        for (int j = 0; j < 32; j += 8)
            tile[ty + j][tx] = Wkv[(long)(r0 + ty + j) * KVDIM + c0 + tx];
        __syncthreads();
#pragma unroll
        for (int j = 0; j < 32; j += 8)
            WkvT[(long)(c0 + ty + j) * DIM + r0 + tx] = f2bf(tile[tx][ty + j]);
        return;
    }
    b2 -= PRO_WKV;
    if (b2 < PRO_MEM) {                        // Memory f32 -> bf16
        const int i = (b2 * 256 + t) * 4;
        const float4 v = *(const float4*)(Memory + i);
        ushort4 o;
        o.x = f2bf(v.x); o.y = f2bf(v.y); o.z = f2bf(v.z); o.w = f2bf(v.w);
        *(ushort4*)(Mbf + i) = o;
        return;
    }
    b2 -= PRO_MEM;
    {                                          // zero simenc (16 blocks)
        const int i = (b2 * 256 + t) * 4;
        uint4 z; z.x = z.y = z.z = z.w = 0u;
        *(uint4*)(simenc + i) = z;
    }
}

// ---------- exclusive scan across 1024 threads ----------
__device__ __forceinline__ unsigned scan1024_excl(unsigned v, unsigned* wsum)
{
    const int lane = threadIdx.x & 63, wv = threadIdx.x >> 6;
    __syncthreads();
    unsigned x = v;
#pragma unroll
    for (int o = 1; o < 64; o <<= 1) {
        unsigned y = __shfl_up(x, o, 64);
        if (lane >= o) x += y;
    }
    if (lane == 63) wsum[wv] = x;
    __syncthreads();
    if (threadIdx.x < 16) {
        unsigned w2 = wsum[threadIdx.x];
#pragma unroll
        for (int o = 1; o < 16; o <<= 1) {
            unsigned y = __shfl_up(w2, o, 64);
            if ((int)threadIdx.x >= o) w2 += y;
        }
        wsum[threadIdx.x] = w2;
    }
    __syncthreads();
    const unsigned off = (wv > 0) ? wsum[wv - 1] : 0u;
    return off + x - v;
}

// ---------- clustered per-wave histogram add (for concentrated distributions) ----------
__device__ __forceinline__ void clustered_add(unsigned* hist, unsigned bin)
{
    bool pending = true;
    while (__any(pending)) {
        const unsigned long long mk = __ballot(pending);
        const int lead = (int)__ffsll(mk) - 1;
        const unsigned lbin = (unsigned)__shfl((int)bin, lead, 64);
        const unsigned long long same = __ballot(pending && (bin == lbin));
        if ((int)(threadIdx.x & 63) == lead)
            atomicAdd(&hist[lbin], (unsigned)__popcll(same));
        if (bin == lbin) pending = false;
    }
}

// ---------- exact top-k via radix select (hybrid: clustered pass-3, private passes 2-0) ----------
#define SEL_T 1024
#define SEL_CH (N_DATA / SEL_T)
__global__ __launch_bounds__(SEL_T)
void select_topk(const unsigned* __restrict__ key, int* __restrict__ idxo, int k)
{
    __shared__ unsigned whist[16][256];
    __shared__ unsigned hist[256];
    __shared__ unsigned wsum[16];
    __shared__ unsigned sh_bin, sh_r;
    const int t = threadIdx.x;
    const int wv = t >> 6;
    const int base = t * SEL_CH;

    unsigned kreg[SEL_CH];
    {
        const uint4* kp = (const uint4*)(key + base);
#pragma unroll
        for (int q = 0; q < SEL_CH / 4; ++q) {
            const uint4 v = kp[q];
            kreg[q * 4 + 0] = v.x; kreg[q * 4 + 1] = v.y;
            kreg[q * 4 + 2] = v.z; kreg[q * 4 + 3] = v.w;
        }
    }

    unsigned prefix = 0, mask = 0;
    unsigned r = (unsigned)k;
    for (int p = 3; p >= 0; --p) {
        __syncthreads();
        if (p == 3) {
            if (t < 256) hist[t] = 0u;
            __syncthreads();
#pragma unroll
            for (int c = 0; c < SEL_CH; ++c)
                clustered_add(hist, kreg[c] >> 24);
        } else {
            for (int i = t; i < 16 * 256; i += SEL_T) ((unsigned*)whist)[i] = 0u;
            __syncthreads();
#pragma unroll
            for (int c = 0; c < SEL_CH; ++c) {
                const unsigned kv = kreg[c];
                if ((kv & mask) == prefix)
                    atomicAdd(&whist[wv][(kv >> (p * 8)) & 255u], 1u);
            }
            __syncthreads();
            if (t < 256) {
                unsigned s = 0;
#pragma unroll
                for (int wq = 0; wq < 16; ++wq) s += whist[wq][t];
                hist[t] = s;
            }
        }
        __syncthreads();
        if (t < 64) {
            const int b0 = 255 - 4 * t;
            const unsigned c = hist[b0] + hist[b0 - 1] + hist[b0 - 2] + hist[b0 - 3];
            unsigned x = c;
#pragma unroll
            for (int o = 1; o < 64; o <<= 1) {
                unsigned y = __shfl_up(x, o, 64);
                if (t >= o) x += y;
            }
            const unsigned pre = x - c;
            if (pre < r && r <= x) {
                unsigned cum = pre;
#pragma unroll
                for (int j = 0; j < 4; ++j) {
                    const int b = b0 - j;
                    cum += hist[b];
                    if (cum >= r) { sh_bin = (unsigned)b; sh_r = r - (cum - hist[b]); break; }
                }
            }
        }
        __syncthreads();
        prefix |= sh_bin << (p * 8);
        mask |= 255u << (p * 8);
        r = sh_r;
    }
    const unsigned thr = prefix;
    const unsigned ties = r;

    unsigned ceq = 0;
#pragma unroll
    for (int c = 0; c < SEL_CH; ++c) ceq += (kreg[c] == thr) ? 1u : 0u;
    const unsigned eqbase = scan1024_excl(ceq, wsum);
    unsigned eq = eqbase, csel = 0;
#pragma unroll
    for (int c = 0; c < SEL_CH; ++c) {
        const unsigned kv = kreg[c];
        bool s;
        if (kv == thr) { s = (eq < ties); ++eq; }
        else s = (kv > thr);
        csel += s ? 1u : 0u;
    }
    unsigned pos = scan1024_excl(csel, wsum);
    eq = eqbase;
#pragma unroll
    for (int c = 0; c < SEL_CH; ++c) {
        const unsigned kv = kreg[c];
        bool s;
        if (kv == thr) { s = (eq < ties); ++eq; }
        else s = (kv > thr);
        if (s) idxo[pos++] = base + c;
    }
}

// ---------- host orchestration ----------
extern "C" void kernel_launch(void* const* d_in, const int* in_sizes, int n_in,
                              void* d_out, int out_size, void* d_ws, size_t ws_size,
                              hipStream_t stream)
{
    (void)in_sizes; (void)n_in; (void)out_size; (void)ws_size;
    const float* data   = (const float*)d_in[0];
    const float* Memory = (const float*)d_in[1];
    const float* Wkv    = (const float*)d_in[2];
    const float* Wq     = (const float*)d_in[3];
    const float* Wm     = (const float*)d_in[4];
    const float* bm     = (const float*)d_in[5];
    float* out = (float*)d_out;

    char* w = (char*)d_ws;
    unsigned* simenc = (unsigned*)(w + 0);             // 64K
    int*   idx     = (int*)  (w + 65536);              // 16K
    float* lse     = (float*)(w + 81920);              // 64K
    float* mlp     = (float*)(w + 147456);             // 64K
    float* Ma      = (float*)(w + 262144);             // 1M
    float* Mb      = (float*)(w + 1310720);            // 1M
    u16*   Mbf0    = (u16*)  (w + 2359296);            // 512K
    u16*   MT_bf   = (u16*)  (w + 2883584);            // 512K
    u16*   WqT_bf  = (u16*)  (w + 3407872);            // 1M (2 layers)
    u16*   WmT_bf  = (u16*)  (w + 4456448);            // 1M
    u16*   WkvT_bf = (u16*)  (w + 5505024);            // 1M
    u16*   o_bf    = (u16*)  (w + 7077888);            // 512K
    u16*   data_bf = (u16*)  (w + 8650752);            // 16M
    u16*   kvsel_bf= (u16*)  (w + 25427968);           // 8M  [4096][1024] (K half used)
    u16*   vT_bf   = (u16*)  (w + 33816576);           // 4M  [8*64][4096]
    float* oPart   = (float*)(w + 38010880);           // 4M
    float* mPart   = (float*)(w + 42205184);           // 64K
    float* lPart   = (float*)(w + 42270720);           // 64K
    u16*   logits_bf = (u16*)(w + 54788096);           // 16M [16384][512] (p)
    u16*   Mbfa    = (u16*)  (w + 88342528);           // 512K
    u16*   Mbfb    = (u16*)  (w + 88866816);           // 512K

    // fused prologue (1 dispatch): conversions + transposes + simenc zero
    prologue<<<PRO_DATA + PRO_W4 + PRO_WKV + PRO_MEM + PRO_SIM, 256, 0, stream>>>(
        data, Memory, Wkv, Wq, Wm, data_bf, Mbf0, WkvT_bf, WqT_bf, WmT_bf, simenc);

    auto sim_select_kv = [&](const u16* Mrows_bf) {
        mfma_gemm<2, 2, false, 2, false, false><<<dim3(128, 4, 1), 256, 0, stream>>>(
            data_bf, Mrows_bf, nullptr, nullptr, nullptr, simenc, nullptr,
            nullptr, nullptr, nullptr,
            DIM, DIM, DIM, 0, 0, 0, 0, 1, 0, SCALE);
        select_topk<<<1, SEL_T, 0, stream>>>(simenc, idx, KSEL);
        mfma_gemm<2, 2, true, 3, false, false><<<dim3(32, 8, 1), 256, 0, stream>>>(
            data_bf, WkvT_bf, nullptr, idx, kvsel_bf, nullptr, vT_bf,
            nullptr, nullptr, nullptr,
            DIM, DIM, DIM, KVDIM, 0, 0, 0, 1, 0, 1.0f);
    };

    auto cross = [&](const float* Mcur, const u16* Mcur_bf, float* Mnext, u16* Mnext_bf,
                     int l, u16* MTout) {
        flash_att<<<dim3(8, NH, NSPLIT), 256, 0, stream>>>(
            Mcur_bf, WqT_bf + (long)l * DIM * DIM, kvsel_bf, vT_bf, oPart, mPart, lPart);
        flash_combine<<<64, 256, 0, stream>>>(oPart, mPart, lPart, o_bf);
        // Wm GEMM + bias + residual + LayerNorm fused (32 blocks); zeroes simenc
        wmln<<<32, 512, 0, stream>>>(
            o_bf, WmT_bf + (long)l * DIM * DIM, bm + (long)l * DIM, Mcur,
            Mnext, Mnext_bf, simenc, MTout);
    };

    const float* Mcur = Memory;
    const u16*  curbf = Mbf0;
    float* Mnext = Ma;
    u16*   nextbf = Mbfa;
    sim_select_kv(curbf);
    for (int it = 0; it < 2; ++it) {
        for (int l = 0; l < 2; ++l) {
            const bool last = (it == 1 && l == 1);
            cross(Mcur, curbf, Mnext, nextbf, l, last ? MT_bf : nullptr);
            Mcur = Mnext; curbf = nextbf;
            Mnext = (Mcur == Ma) ? Mb : Ma;
            nextbf = (curbf == Mbfa) ? Mbfb : Mbfa;
        }
        if (it == 0) sim_select_kv(curbf);
    }

    // final: fused logits+softmax (p -> logits_bf), then p@M with fused loss reduction
    mfma_gemm_sm<<<N_DATA / 64, 512, 0, stream>>>(
        data_bf, curbf, logits_bf, out, lse, mlp, SCALE);
    mfma_gemm<2, 2, false, 0, false, true><<<dim3(128, 4, 1), 256, 0, stream>>>(
        logits_bf, MT_bf, nullptr, nullptr, out + N_DATA, nullptr, nullptr,
        lse, mlp, out + N_DATA + (long)N_DATA * DIM,
        MEM, MEM, MEM, DIM, 0, 0, 0, 1, 0, 1.0f);
}